// Round 1
// baseline (29962.357 us; speedup 1.0000x reference)
//
#include <hip/hip_runtime.h>
#include <math.h>

// Problem: ImuModel — 2x ConvLSTM2D(96, 3x3, SAME) + BN + Flatten + Dense(10)
// B=16 T=64 H=W=16 C=6 F=96, 4F=384 gates, NC=10
//
// Implementation v1 (fp32 correctness baseline):
//   per timestep t:
//     convgate<6,96>  : gates = conv(x_t,Wx0) + conv(h0,Wh0) + b0   (implicit GEMM)
//     lstm_pointwise  : h0,c0 update; h0bn = BN0(h0)
//     convgate<96,96> : gates = conv(h0bn,Wx1) + conv(h1,Wh1) + b1
//     lstm_pointwise  : h1,c1 update; hall[t] = BN1(h1)
//   dense_partial/reduce : out = flatten(hall) @ Wd + bd  (deterministic 2-stage)
//
// Workspace (floats): h0,c0,h1,c1 (4*393216) + h0bn (393216) + gates (1572864)
//                     + hall (25165824) + partial (768*160)  = 115.3 MB

#define HH 16
#define WW 16
#define FF 96
#define NG 384           // 4*F
#define MTOT 4096        // B*H*W

__device__ __forceinline__ float hsig(float x) {
    return fminf(fmaxf(0.2f * x + 0.5f, 0.0f), 1.0f);
}

// ---------------------------------------------------------------------------
// Implicit-GEMM conv producing all 4F gate channels.
// C[m][n] = bias[n] + sum_k A[m][k]*W[k][n], where A is im2col of two inputs
// (in0 with CIN0 channels contributes K0=9*CIN0 rows, then in1 with CIN1).
// M=4096 (b,y,x), N=384. Tile: BM=64, BN=64, BK=16; 256 thr, 4x4 per thread.
// ---------------------------------------------------------------------------
template<int CIN0, int CIN1>
__global__ __launch_bounds__(256) void convgate(
    const float* __restrict__ in0, int in0_bs,
    const float* __restrict__ W0,
    const float* __restrict__ in1, int in1_bs,
    const float* __restrict__ W1,
    const float* __restrict__ bias,
    float* __restrict__ gates)
{
    constexpr int K0 = 9 * CIN0;
    constexpr int K1 = 9 * CIN1;
    constexpr int KT = K0 + K1;
    constexpr int BK = 16;

    const int m0 = blockIdx.x * 64;
    const int n0 = blockIdx.y * 64;
    const int tid = threadIdx.x;
    const int tx = tid & 15;
    const int ty = tid >> 4;

    __shared__ float As[BK][64];   // [k][m]
    __shared__ float Bs[BK][64];   // [k][n]

    float acc[4][4] = {};

    // loader decode: element e = tid + 256*i  ->  lane=tid&63, k=(tid>>6)+4*i
    const int am = tid & 63;            // m-offset (A) / n-offset (B)
    const int ak = tid >> 6;            // base k (0..3)
    const int mg = m0 + am;
    const int ay = (mg >> 4) & 15;
    const int ax = mg & 15;
    const int b  = mg >> 8;             // uniform across block (64 | 256)

    const float4 bias4 = *(const float4*)(&bias[n0 + tx * 4]);

    for (int kc = 0; kc < KT; kc += BK) {
        // ---- load A tile (im2col gather) ----
        #pragma unroll
        for (int i = 0; i < 4; ++i) {
            const int k  = ak + 4 * i;
            const int kg = kc + k;
            float va = 0.0f;
            if (kg < K0) {
                const int q  = kg / CIN0;
                const int c  = kg - q * CIN0;
                const int ky = q / 3;
                const int kx = q - 3 * ky;
                const int yy = ay + ky - 1;
                const int xx = ax + kx - 1;
                if ((unsigned)yy < 16u && (unsigned)xx < 16u)
                    va = in0[b * in0_bs + (yy * 16 + xx) * CIN0 + c];
            } else if (kg < KT) {
                const int kr = kg - K0;
                const int q  = kr / CIN1;
                const int c  = kr - q * CIN1;
                const int ky = q / 3;
                const int kx = q - 3 * ky;
                const int yy = ay + ky - 1;
                const int xx = ax + kx - 1;
                if ((unsigned)yy < 16u && (unsigned)xx < 16u)
                    va = in1[b * in1_bs + (yy * 16 + xx) * CIN1 + c];
            }
            As[k][am] = va;
        }
        // ---- load B tile (weights, coalesced) ----
        #pragma unroll
        for (int i = 0; i < 4; ++i) {
            const int k  = ak + 4 * i;
            const int kg = kc + k;
            float vb = 0.0f;
            if (kg < K0)       vb = W0[kg * NG + n0 + am];
            else if (kg < KT)  vb = W1[(kg - K0) * NG + n0 + am];
            Bs[k][am] = vb;
        }
        __syncthreads();

        #pragma unroll
        for (int kk = 0; kk < BK; ++kk) {
            const float4 av = *(const float4*)(&As[kk][ty * 4]);
            const float4 bv = *(const float4*)(&Bs[kk][tx * 4]);
            const float a[4] = {av.x, av.y, av.z, av.w};
            const float bb[4] = {bv.x, bv.y, bv.z, bv.w};
            #pragma unroll
            for (int i = 0; i < 4; ++i)
                #pragma unroll
                for (int j = 0; j < 4; ++j)
                    acc[i][j] = fmaf(a[i], bb[j], acc[i][j]);
        }
        __syncthreads();
    }

    #pragma unroll
    for (int i = 0; i < 4; ++i) {
        const int m = m0 + ty * 4 + i;
        float4 o;
        o.x = acc[i][0] + bias4.x;
        o.y = acc[i][1] + bias4.y;
        o.z = acc[i][2] + bias4.z;
        o.w = acc[i][3] + bias4.w;
        *(float4*)(&gates[m * NG + n0 + tx * 4]) = o;
    }
}

// ---------------------------------------------------------------------------
// LSTM pointwise: gate nonlinearities, state update, BN'd hidden output.
// gates: [4096][384] (i,f,c,o each 96 wide).  h,c: [4096][96].  hbn: [4096][96]
// ---------------------------------------------------------------------------
__global__ __launch_bounds__(256) void lstm_pointwise(
    const float* __restrict__ gates,
    float* __restrict__ h, float* __restrict__ cst,
    const float* __restrict__ gam, const float* __restrict__ bet,
    const float* __restrict__ mu,  const float* __restrict__ var,
    float* __restrict__ hbn)
{
    const int idx = blockIdx.x * 256 + threadIdx.x;   // < 393216
    const int m = idx / FF;
    const int f = idx - m * FF;
    const int gb = m * NG + f;
    const float gi = gates[gb];
    const float gf = gates[gb + FF];
    const float gc = gates[gb + 2 * FF];
    const float go = gates[gb + 3 * FF];

    const float i_ = hsig(gi);
    const float f_ = hsig(gf);
    const float o_ = hsig(go);
    const float cn = f_ * cst[idx] + i_ * tanhf(gc);
    const float hn = o_ * tanhf(cn);
    cst[idx] = cn;
    h[idx]   = hn;

    const float s = gam[f] / sqrtf(var[f] + 1e-3f);
    hbn[idx] = (hn - mu[f]) * s + bet[f];
}

// ---------------------------------------------------------------------------
// Dense: out[b][nc] = sum_k flat[b][k] * Wd[k][nc] + bd[nc]
// flat[b][k] with k = t*24576 + r maps to hall[t*393216 + b*24576 + r].
// Stage 1: 768 blocks x 2048 k each (24576 % 2048 == 0 -> no t straddle).
// ---------------------------------------------------------------------------
__global__ void dense_partial(const float* __restrict__ hall,
                              const float* __restrict__ Wd,
                              float* __restrict__ partial)
{
    const int k0 = blockIdx.x * 2048;
    const int tt = k0 / 24576;
    const int r0 = k0 - tt * 24576;
    const int t  = threadIdx.x;          // 0..159
    const int b  = t / 10;
    const int nc = t - b * 10;
    const float* hp = hall + (tt * 16 + b) * 24576 + r0;
    const float* wp = Wd + (size_t)k0 * 10 + nc;
    float acc = 0.0f;
    #pragma unroll 4
    for (int j = 0; j < 2048; ++j)
        acc = fmaf(hp[j], wp[(size_t)j * 10], acc);
    partial[blockIdx.x * 160 + t] = acc;
}

__global__ void dense_reduce(const float* __restrict__ partial,
                             const float* __restrict__ bd,
                             float* __restrict__ out)
{
    const int t = threadIdx.x;           // 0..159
    const int nc = t - (t / 10) * 10;
    float acc = bd[nc];
    for (int p = 0; p < 768; ++p) acc += partial[p * 160 + t];
    out[t] = acc;
}

// ---------------------------------------------------------------------------
extern "C" void kernel_launch(void* const* d_in, const int* in_sizes, int n_in,
                              void* d_out, int out_size, void* d_ws, size_t ws_size,
                              hipStream_t stream)
{
    const float* x   = (const float*)d_in[0];
    const float* Wx0 = (const float*)d_in[1];
    const float* Wh0 = (const float*)d_in[2];
    const float* b0  = (const float*)d_in[3];
    const float* g0  = (const float*)d_in[4];
    const float* be0 = (const float*)d_in[5];
    const float* mu0 = (const float*)d_in[6];
    const float* v0  = (const float*)d_in[7];
    const float* Wx1 = (const float*)d_in[8];
    const float* Wh1 = (const float*)d_in[9];
    const float* b1  = (const float*)d_in[10];
    const float* g1  = (const float*)d_in[11];
    const float* be1 = (const float*)d_in[12];
    const float* mu1 = (const float*)d_in[13];
    const float* v1  = (const float*)d_in[14];
    const float* Wd  = (const float*)d_in[15];
    const float* bd  = (const float*)d_in[16];
    float* out = (float*)d_out;

    float* ws = (float*)d_ws;
    float* h0      = ws;                       // 393216
    float* c0      = h0 + 393216;              // 393216
    float* h1      = c0 + 393216;              // 393216
    float* c1      = h1 + 393216;              // 393216
    float* h0bn    = c1 + 393216;              // 393216
    float* gates   = h0bn + 393216;            // 1572864
    float* hall    = gates + 1572864;          // 25165824
    float* partial = hall + 25165824;          // 122880

    // zero initial LSTM states (h0,c0,h1,c1 contiguous)
    hipMemsetAsync(h0, 0, (size_t)4 * 393216 * sizeof(float), stream);

    const dim3 cgrid(64, 6);
    for (int t = 0; t < 64; ++t) {
        convgate<6, 96><<<cgrid, 256, 0, stream>>>(
            x + (size_t)t * 1536, 98304, Wx0, h0, 24576, Wh0, b0, gates);
        lstm_pointwise<<<1536, 256, 0, stream>>>(
            gates, h0, c0, g0, be0, mu0, v0, h0bn);
        convgate<96, 96><<<cgrid, 256, 0, stream>>>(
            h0bn, 24576, Wx1, h1, 24576, Wh1, b1, gates);
        lstm_pointwise<<<1536, 256, 0, stream>>>(
            gates, h1, c1, g1, be1, mu1, v1, hall + (size_t)t * 393216);
    }

    dense_partial<<<768, 160, 0, stream>>>(hall, Wd, partial);
    dense_reduce<<<1, 160, 0, stream>>>(partial, bd, out);
}

// Round 2
// 4386.056 us; speedup vs baseline: 6.8313x; 6.8313x over previous
//
#include <hip/hip_runtime.h>
#include <math.h>

// ImuModel v2: bf16-MFMA implicit-GEMM ConvLSTM (fp32 accumulate)
// B=16 T=64 H=W=16 C=6 F=96, gates 4F=384, out [16,10]
//
// Per step t:
//   conv_mfma<32>(xpad_t[32ch], h0[96ch], Wt0, b0) -> gates   (K=1152)
//   pw(gates, c0) -> h0(bf16), h0bn(bf16)
//   conv_mfma<96>(h0bn, h1, Wt1, b1) -> gates                 (K=1728)
//   pw(gates, c1) -> h1(bf16), hall_t(bf16)
// dense_partial/reduce over hall (bf16) x Wd (fp32)
//
// Tiling: BM=64, BN=96, 4 waves of 32x48 (2x3 frags of 16x16), K-step 32.
// LDS: As[64][40] bf16 (pad 40 -> 2-way bank alias = free), Bs[96][40].

typedef __attribute__((ext_vector_type(8))) short     bf16x8;
typedef __attribute__((ext_vector_type(8))) unsigned short u16x8;
typedef __attribute__((ext_vector_type(4))) float     f32x4;
typedef unsigned short u16;

__device__ __forceinline__ float hsig(float x) {
    return fminf(fmaxf(0.2f * x + 0.5f, 0.0f), 1.0f);
}
__device__ __forceinline__ float bf2f(u16 u) {
    union { unsigned int i; float f; } v; v.i = ((unsigned int)u) << 16; return v.f;
}
__device__ __forceinline__ u16 f2bf(float f) {
    union { float f; unsigned int i; } v; v.f = f;
    unsigned int r = (v.i + 0x7FFFu + ((v.i >> 16) & 1u)) >> 16;   // RNE
    return (u16)r;
}

// ---------------------------------------------------------------------------
// prep: x [16][64][256][6] f32 -> xpad [64][16][256][32] bf16 (zero-padded ch)
// ---------------------------------------------------------------------------
__global__ __launch_bounds__(256) void prep_x(const float* __restrict__ x,
                                              u16* __restrict__ xpad)
{
    const int idx = blockIdx.x * 256 + threadIdx.x;      // < 262144 = t*4096+b*256+p
    const int t = idx >> 12, b = (idx >> 8) & 15, p = idx & 255;
    const float* src = x + (((size_t)b * 64 + t) * 256 + p) * 6;
    u16x8 v0 = {};
    v0[0] = f2bf(src[0]); v0[1] = f2bf(src[1]); v0[2] = f2bf(src[2]);
    v0[3] = f2bf(src[3]); v0[4] = f2bf(src[4]); v0[5] = f2bf(src[5]);
    u16x8 z = {};
    u16x8* dst = (u16x8*)(xpad + (size_t)idx * 32);
    dst[0] = v0; dst[1] = z; dst[2] = z; dst[3] = z;
}

// Wt0[n][k], k<288: x-part (q=k>>5, c=k&31, real if c<6), k>=288: Wh0[k-288]
__global__ __launch_bounds__(256) void wtrans0(const float* __restrict__ Wx0,
                                               const float* __restrict__ Wh0,
                                               u16* __restrict__ Wt0)
{
    const int idx = blockIdx.x * 256 + threadIdx.x;      // < 384*1152
    const int n = idx / 1152, k = idx - n * 1152;
    float v = 0.0f;
    if (k < 288) {
        const int q = k >> 5, c = k & 31;
        if (c < 6) v = Wx0[(q * 6 + c) * 384 + n];
    } else {
        v = Wh0[(k - 288) * 384 + n];
    }
    Wt0[idx] = f2bf(v);
}

// Wt1[n][k], k<864: Wx1[k], else Wh1[k-864]
__global__ __launch_bounds__(256) void wtrans1(const float* __restrict__ Wx1,
                                               const float* __restrict__ Wh1,
                                               u16* __restrict__ Wt1)
{
    const int idx = blockIdx.x * 256 + threadIdx.x;      // < 384*1728
    const int n = idx / 1728, k = idx - n * 1728;
    const float v = (k < 864) ? Wx1[k * 384 + n] : Wh1[(k - 864) * 384 + n];
    Wt1[idx] = f2bf(v);
}

// ---------------------------------------------------------------------------
// MFMA implicit-GEMM conv: gates[m][n] = bias[n] + sum_k A[m][k] Wt[n][k]
// A = im2col( in0 [4096][C0] (K0=9*C0) ++ in1 [4096][96] (864) ), all bf16.
// Grid (64,4): m0=bx*64, n0=by*96. 256 thr = 4 waves (2x2), wave tile 32x48.
// ---------------------------------------------------------------------------
template<int C0>
__global__ __launch_bounds__(256) void conv_mfma(
    const u16* __restrict__ in0, const u16* __restrict__ in1,
    const u16* __restrict__ Wt,  const float* __restrict__ bias,
    float* __restrict__ gates)
{
    constexpr int K0 = 9 * C0;
    constexpr int KT = K0 + 864;
    constexpr int NSTEP = KT / 32;
    constexpr int NS0 = K0 / 32;          // steps belonging to in0

    __shared__ u16 As[64][40];
    __shared__ u16 Bs[96][40];

    const int tid  = threadIdx.x;
    const int m0   = blockIdx.x * 64;
    const int n0   = blockIdx.y * 96;
    const int lane = tid & 63;
    const int wave = tid >> 6;
    const int wm   = wave >> 1;           // 0..1 (m half)
    const int wn   = wave & 1;            // 0..1 (n half)
    const int fr   = lane & 15;
    const int fg   = lane >> 4;

    // staging ids: 4 lanes per row, 16B (8 bf16) each
    const int arow = tid >> 2;            // 0..63
    const int seg  = tid & 3;
    const int mg = m0 + arow;
    const int py = (mg >> 4) & 15;
    const int px = mg & 15;
    const int pb = mg >> 8;

    f32x4 acc[2][3];
#pragma unroll
    for (int i = 0; i < 2; ++i)
#pragma unroll
        for (int j = 0; j < 3; ++j) acc[i][j] = (f32x4){0.f, 0.f, 0.f, 0.f};

    for (int ks = 0; ks < NSTEP; ++ks) {
        // ---- decode k-chunk -> (src, q, c0) ----
        const u16* src; int CC, q, c0;
        if (C0 == 32) {
            if (ks < NS0) { src = in0; CC = 32; q = ks; c0 = 0; }
            else { const int s = ks - NS0; src = in1; CC = 96; q = s / 3; c0 = (s - 3 * (s / 3)) * 32; }
        } else {
            const int s = (ks < NS0) ? ks : ks - NS0;
            src = (ks < NS0) ? in0 : in1; CC = 96;
            q = s / 3; c0 = (s - 3 * q) * 32;
        }
        const int yy = py + q / 3 - 1;
        const int xx = px + (q - 3 * (q / 3)) - 1;
        const bool valid = ((unsigned)yy < 16u) && ((unsigned)xx < 16u);

        // ---- issue global loads ----
        u16x8 va = {};
        if (valid)
            va = *(const u16x8*)(src + ((size_t)(pb * 256 + yy * 16 + xx)) * CC + c0 + seg * 8);
        const int koff = ks * 32 + seg * 8;
        const u16x8 vb0 = *(const u16x8*)(Wt + (size_t)(n0 + arow) * KT + koff);
        u16x8 vb1 = {};
        if (tid < 128)
            vb1 = *(const u16x8*)(Wt + (size_t)(n0 + 64 + arow) * KT + koff);

        __syncthreads();   // previous iteration's frag reads done
        *(u16x8*)(&As[arow][seg * 8]) = va;
        *(u16x8*)(&Bs[arow][seg * 8]) = vb0;
        if (tid < 128) *(u16x8*)(&Bs[64 + arow][seg * 8]) = vb1;
        __syncthreads();

        // ---- fragments + MFMA ----
        bf16x8 af[2], bq[3];
#pragma unroll
        for (int mf = 0; mf < 2; ++mf)
            af[mf] = *(const bf16x8*)(&As[wm * 32 + mf * 16 + fr][fg * 8]);
#pragma unroll
        for (int nf = 0; nf < 3; ++nf)
            bq[nf] = *(const bf16x8*)(&Bs[wn * 48 + nf * 16 + fr][fg * 8]);
#pragma unroll
        for (int mf = 0; mf < 2; ++mf)
#pragma unroll
            for (int nf = 0; nf < 3; ++nf)
                acc[mf][nf] = __builtin_amdgcn_mfma_f32_16x16x32_bf16(
                    af[mf], bq[nf], acc[mf][nf], 0, 0, 0);
    }

    // ---- epilogue: C/D layout col=lane&15, row=(lane>>4)*4+r ----
#pragma unroll
    for (int nf = 0; nf < 3; ++nf) {
        const int n = n0 + wn * 48 + nf * 16 + fr;
        const float bi = bias[n];
#pragma unroll
        for (int mf = 0; mf < 2; ++mf) {
            const int mrow = m0 + wm * 32 + mf * 16 + fg * 4;
#pragma unroll
            for (int r = 0; r < 4; ++r)
                gates[(size_t)(mrow + r) * 384 + n] = acc[mf][nf][r] + bi;
        }
    }
}

// ---------------------------------------------------------------------------
// pointwise: gates -> (hraw bf16, c f32, hbn bf16)   [4096 m][96 f]
// ---------------------------------------------------------------------------
__global__ __launch_bounds__(256) void pw(
    const float* __restrict__ gates, float* __restrict__ cst,
    u16* __restrict__ hraw, u16* __restrict__ hbn,
    const float* __restrict__ gam, const float* __restrict__ bet,
    const float* __restrict__ mu,  const float* __restrict__ var)
{
    const int idx = blockIdx.x * 256 + threadIdx.x;     // < 98304
    const int m = idx / 24, f0 = (idx - m * 24) * 4;
    const float* gb = gates + (size_t)m * 384 + f0;
    const f32x4 gi = *(const f32x4*)gb;
    const f32x4 gf = *(const f32x4*)(gb + 96);
    const f32x4 gc = *(const f32x4*)(gb + 192);
    const f32x4 go = *(const f32x4*)(gb + 288);
    float* cp = cst + m * 96 + f0;
    f32x4 cc = *(const f32x4*)cp;
    const f32x4 ga = *(const f32x4*)(gam + f0);
    const f32x4 be = *(const f32x4*)(bet + f0);
    const f32x4 mv = *(const f32x4*)(mu + f0);
    const f32x4 vv = *(const f32x4*)(var + f0);

    u16 hu[4], bu[4];
    f32x4 cn;
#pragma unroll
    for (int j = 0; j < 4; ++j) {
        const float i_ = hsig(gi[j]);
        const float f_ = hsig(gf[j]);
        const float o_ = hsig(go[j]);
        const float c_ = f_ * cc[j] + i_ * tanhf(gc[j]);
        const float h_ = o_ * tanhf(c_);
        cn[j] = c_;
        hu[j] = f2bf(h_);
        const float s = ga[j] * rsqrtf(vv[j] + 1e-3f);
        bu[j] = f2bf((h_ - mv[j]) * s + be[j]);
    }
    *(f32x4*)cp = cn;
    uint2 hp; hp.x = hu[0] | ((unsigned)hu[1] << 16); hp.y = hu[2] | ((unsigned)hu[3] << 16);
    uint2 bp; bp.x = bu[0] | ((unsigned)bu[1] << 16); bp.y = bu[2] | ((unsigned)bu[3] << 16);
    *(uint2*)(hraw + (size_t)m * 96 + f0) = hp;
    *(uint2*)(hbn  + (size_t)m * 96 + f0) = bp;
}

// ---------------------------------------------------------------------------
// dense over hall (bf16): out[b][nc] = sum_k flat[b][k] Wd[k][nc] + bd[nc]
// ---------------------------------------------------------------------------
__global__ void dense_partial(const u16* __restrict__ hall,
                              const float* __restrict__ Wd,
                              float* __restrict__ partial)
{
    const int k0 = blockIdx.x * 2048;
    const int tt = k0 / 24576;
    const int r0 = k0 - tt * 24576;
    const int t  = threadIdx.x;          // 0..159
    const int b  = t / 10;
    const int nc = t - b * 10;
    const u16* hp = hall + (size_t)(tt * 16 + b) * 24576 + r0;
    const float* wp = Wd + (size_t)k0 * 10 + nc;
    float acc = 0.0f;
    for (int j = 0; j < 2048; j += 8) {
        const u16x8 hv = *(const u16x8*)(hp + j);
#pragma unroll
        for (int u = 0; u < 8; ++u)
            acc = fmaf(bf2f(hv[u]), wp[(size_t)(j + u) * 10], acc);
    }
    partial[blockIdx.x * 160 + t] = acc;
}

__global__ void dense_reduce(const float* __restrict__ partial,
                             const float* __restrict__ bd,
                             float* __restrict__ out)
{
    const int t = threadIdx.x;           // 0..159
    const int nc = t - (t / 10) * 10;
    float acc = bd[nc];
    for (int p = 0; p < 768; ++p) acc += partial[p * 160 + t];
    out[t] = acc;
}

// ---------------------------------------------------------------------------
extern "C" void kernel_launch(void* const* d_in, const int* in_sizes, int n_in,
                              void* d_out, int out_size, void* d_ws, size_t ws_size,
                              hipStream_t stream)
{
    const float* x   = (const float*)d_in[0];
    const float* Wx0 = (const float*)d_in[1];
    const float* Wh0 = (const float*)d_in[2];
    const float* b0  = (const float*)d_in[3];
    const float* g0  = (const float*)d_in[4];
    const float* be0 = (const float*)d_in[5];
    const float* mu0 = (const float*)d_in[6];
    const float* v0  = (const float*)d_in[7];
    const float* Wx1 = (const float*)d_in[8];
    const float* Wh1 = (const float*)d_in[9];
    const float* b1  = (const float*)d_in[10];
    const float* g1  = (const float*)d_in[11];
    const float* be1 = (const float*)d_in[12];
    const float* mu1 = (const float*)d_in[13];
    const float* v1  = (const float*)d_in[14];
    const float* Wd  = (const float*)d_in[15];
    const float* bd  = (const float*)d_in[16];
    float* out = (float*)d_out;

    char* base = (char*)d_ws;
    u16*   h0    = (u16*)(base);                       //   786432 B
    u16*   h1    = (u16*)(base + 786432);              //   786432 B
    float* c0    = (float*)(base + 1572864);           //  1572864 B
    float* c1    = (float*)(base + 3145728);           //  1572864 B
    u16*   h0bn  = (u16*)(base + 4718592);             //   786432 B
    float* gates = (float*)(base + 5505024);           //  6291456 B
    u16*   xpad  = (u16*)(base + 11796480);            // 16777216 B
    u16*   Wt0   = (u16*)(base + 28573696);            //   884736 B
    u16*   Wt1   = (u16*)(base + 29458432);            //  1327104 B
    u16*   hall  = (u16*)(base + 30785536);            // 50331648 B
    float* part  = (float*)(base + 81117184);          //   491520 B

    // zero initial states h0,h1 (bf16) + c0,c1 (f32), contiguous
    hipMemsetAsync(base, 0, 4718592, stream);

    prep_x <<<1024, 256, 0, stream>>>(x, xpad);
    wtrans0<<<1728, 256, 0, stream>>>(Wx0, Wh0, Wt0);
    wtrans1<<<2592, 256, 0, stream>>>(Wx1, Wh1, Wt1);

    const dim3 cgrid(64, 4);
    for (int t = 0; t < 64; ++t) {
        conv_mfma<32><<<cgrid, 256, 0, stream>>>(
            xpad + (size_t)t * 131072, h0, Wt0, b0, gates);
        pw<<<384, 256, 0, stream>>>(gates, c0, h0, h0bn, g0, be0, mu0, v0);
        conv_mfma<96><<<cgrid, 256, 0, stream>>>(
            h0bn, h1, Wt1, b1, gates);
        pw<<<384, 256, 0, stream>>>(gates, c1, h1, hall + (size_t)t * 393216,
                                    g1, be1, mu1, v1);
    }

    dense_partial<<<768, 160, 0, stream>>>(hall, Wd, part);
    dense_reduce <<<1, 160, 0, stream>>>(part, bd, out);
}

// Round 3
// 3506.107 us; speedup vs baseline: 8.5458x; 1.2510x over previous
//
#include <hip/hip_runtime.h>
#include <math.h>

// ImuModel v3: bf16-MFMA implicit-GEMM ConvLSTM, reg-prefetch double-buffered
// B=16 T=64 H=W=16 C=6 F=96, gates 4F=384, out [16,10]
//
// vs v2: (a) x padded to 8ch (12 taps, 3 zero) -> conv0 K 1152->960
//        (b) conv K-loop: global->reg prefetch of step k+1 issued before the
//            MFMAs of step k; 2 LDS buffers; ONE barrier per step.
//
// Tiling: BM=64, BN=96, 4 waves of 32x48 (2x3 frags of 16x16x32), K-step 32.

typedef __attribute__((ext_vector_type(8))) short     bf16x8;
typedef __attribute__((ext_vector_type(8))) unsigned short u16x8;
typedef __attribute__((ext_vector_type(4))) float     f32x4;
typedef unsigned short u16;

__device__ __forceinline__ float hsig(float x) {
    return fminf(fmaxf(0.2f * x + 0.5f, 0.0f), 1.0f);
}
__device__ __forceinline__ float bf2f(u16 u) {
    union { unsigned int i; float f; } v; v.i = ((unsigned int)u) << 16; return v.f;
}
__device__ __forceinline__ u16 f2bf(float f) {
    union { float f; unsigned int i; } v; v.f = f;
    unsigned int r = (v.i + 0x7FFFu + ((v.i >> 16) & 1u)) >> 16;   // RNE
    return (u16)r;
}

// ---------------------------------------------------------------------------
// prep: x [16][64][256][6] f32 -> xpad [64][16][256][8] bf16 (zero-padded ch)
// ---------------------------------------------------------------------------
__global__ __launch_bounds__(256) void prep_x(const float* __restrict__ x,
                                              u16* __restrict__ xpad)
{
    const int idx = blockIdx.x * 256 + threadIdx.x;      // < 262144 = t*4096+b*256+p
    const int t = idx >> 12, b = (idx >> 8) & 15, p = idx & 255;
    const float* src = x + (((size_t)b * 64 + t) * 256 + p) * 6;
    u16x8 v = {};
    v[0] = f2bf(src[0]); v[1] = f2bf(src[1]); v[2] = f2bf(src[2]);
    v[3] = f2bf(src[3]); v[4] = f2bf(src[4]); v[5] = f2bf(src[5]);
    *(u16x8*)(xpad + (size_t)idx * 8) = v;
}

// Wt0[n][k], KT=960. k<96: tap q=k>>3 (12 taps, q<9 real), ch c=k&7 (c<6 real)
//                    k>=96: Wh0 flat index k-96 (= q*96+c), already matches A.
__global__ __launch_bounds__(256) void wtrans0(const float* __restrict__ Wx0,
                                               const float* __restrict__ Wh0,
                                               u16* __restrict__ Wt0)
{
    const int idx = blockIdx.x * 256 + threadIdx.x;      // < 384*960
    const int n = idx / 960, k = idx - n * 960;
    float v = 0.0f;
    if (k < 96) {
        const int q = k >> 3, c = k & 7;
        if (q < 9 && c < 6) v = Wx0[(q * 6 + c) * 384 + n];
    } else {
        v = Wh0[(k - 96) * 384 + n];
    }
    Wt0[idx] = f2bf(v);
}

// Wt1[n][k], KT=1728. k<864: Wx1[k], else Wh1[k-864]
__global__ __launch_bounds__(256) void wtrans1(const float* __restrict__ Wx1,
                                               const float* __restrict__ Wh1,
                                               u16* __restrict__ Wt1)
{
    const int idx = blockIdx.x * 256 + threadIdx.x;      // < 384*1728
    const int n = idx / 1728, k = idx - n * 1728;
    const float v = (k < 864) ? Wx1[k * 384 + n] : Wh1[(k - 864) * 384 + n];
    Wt1[idx] = f2bf(v);
}

// ---------------------------------------------------------------------------
// MFMA implicit-GEMM conv: gates[m][n] = bias[n] + sum_k A[m][k] Wt[n][k]
// C0=8 : in0 = padded x (8ch, 12 taps -> K0=96),  in1 = h (96ch, K=864)
// C0=96: in0 = h0bn (96ch, 864),                  in1 = h (96ch, 864)
// Grid (64,4): m0=bx*64, n0=by*96. 4 waves (2x2), wave tile 32x48.
// Pipeline: prefetch step k+1 to regs above MFMAs of step k; 2 LDS bufs,
// one __syncthreads per step.
// ---------------------------------------------------------------------------
template<int C0>
__global__ __launch_bounds__(256) void conv_mfma(
    const u16* __restrict__ in0, const u16* __restrict__ in1,
    const u16* __restrict__ Wt,  const float* __restrict__ bias,
    float* __restrict__ gates)
{
    constexpr int K0 = (C0 == 8) ? 96 : 864;
    constexpr int KT = K0 + 864;
    constexpr int NSTEP = KT / 32;
    constexpr int NS0 = K0 / 32;

    __shared__ u16 As[2][64][40];
    __shared__ u16 Bs[2][96][40];

    const int tid  = threadIdx.x;
    const int m0   = blockIdx.x * 64;
    const int n0   = blockIdx.y * 96;
    const int lane = tid & 63;
    const int wave = tid >> 6;
    const int wm   = wave >> 1;
    const int wn   = wave & 1;
    const int fr   = lane & 15;
    const int fg   = lane >> 4;

    const int arow = tid >> 2;            // 0..63
    const int seg  = tid & 3;
    const int mg = m0 + arow;
    const int py = (mg >> 4) & 15;
    const int px = mg & 15;
    const int pb = mg >> 8;

    f32x4 acc[2][3];
#pragma unroll
    for (int i = 0; i < 2; ++i)
#pragma unroll
        for (int j = 0; j < 3; ++j) acc[i][j] = (f32x4){0.f, 0.f, 0.f, 0.f};

    u16x8 va, vb0, vb1;
    auto stage = [&](int ks) {
        u16x8 z = {};
        va = z;
        if (C0 == 8) {
            if (ks < NS0) {
                // x-part: thread's 16B = all 8 channels of tap q
                const int q = ks * 4 + seg;
                const int qd = q / 3;
                const int yy = py + qd - 1;
                const int xx = px + (q - 3 * qd) - 1;
                if (q < 9 && (unsigned)yy < 16u && (unsigned)xx < 16u)
                    va = *(const u16x8*)(in0 + (size_t)((pb << 8) + yy * 16 + xx) * 8);
            } else {
                const int s = ks - NS0;
                const int q = s / 3;
                const int c0 = (s - 3 * q) * 32 + seg * 8;
                const int qd = q / 3;
                const int yy = py + qd - 1;
                const int xx = px + (q - 3 * qd) - 1;
                if ((unsigned)yy < 16u && (unsigned)xx < 16u)
                    va = *(const u16x8*)(in1 + (size_t)((pb << 8) + yy * 16 + xx) * 96 + c0);
            }
        } else {
            const int s = (ks < NS0) ? ks : ks - NS0;
            const u16* src = (ks < NS0) ? in0 : in1;
            const int q = s / 3;
            const int c0 = (s - 3 * q) * 32 + seg * 8;
            const int qd = q / 3;
            const int yy = py + qd - 1;
            const int xx = px + (q - 3 * qd) - 1;
            if ((unsigned)yy < 16u && (unsigned)xx < 16u)
                va = *(const u16x8*)(src + (size_t)((pb << 8) + yy * 16 + xx) * 96 + c0);
        }
        const int koff = ks * 32 + seg * 8;
        vb0 = *(const u16x8*)(Wt + (size_t)(n0 + arow) * KT + koff);
        vb1 = z;
        if (tid < 128)
            vb1 = *(const u16x8*)(Wt + (size_t)(n0 + 64 + arow) * KT + koff);
    };

    // prologue: fill buffer 0
    stage(0);
    *(u16x8*)(&As[0][arow][seg * 8]) = va;
    *(u16x8*)(&Bs[0][arow][seg * 8]) = vb0;
    if (tid < 128) *(u16x8*)(&Bs[0][64 + arow][seg * 8]) = vb1;
    __syncthreads();

    for (int ks = 0; ks < NSTEP; ++ks) {
        const int cur = ks & 1, nxt = cur ^ 1;
        const bool more = (ks + 1 < NSTEP);
        if (more) stage(ks + 1);          // loads fly under frag reads + MFMA

        bf16x8 af[2], bq[3];
#pragma unroll
        for (int mf = 0; mf < 2; ++mf)
            af[mf] = *(const bf16x8*)(&As[cur][wm * 32 + mf * 16 + fr][fg * 8]);
#pragma unroll
        for (int nf = 0; nf < 3; ++nf)
            bq[nf] = *(const bf16x8*)(&Bs[cur][wn * 48 + nf * 16 + fr][fg * 8]);
#pragma unroll
        for (int mf = 0; mf < 2; ++mf)
#pragma unroll
            for (int nf = 0; nf < 3; ++nf)
                acc[mf][nf] = __builtin_amdgcn_mfma_f32_16x16x32_bf16(
                    af[mf], bq[nf], acc[mf][nf], 0, 0, 0);

        if (more) {
            *(u16x8*)(&As[nxt][arow][seg * 8]) = va;      // vmcnt wait here only
            *(u16x8*)(&Bs[nxt][arow][seg * 8]) = vb0;
            if (tid < 128) *(u16x8*)(&Bs[nxt][64 + arow][seg * 8]) = vb1;
            __syncthreads();
        }
    }

    // epilogue: C/D layout col=lane&15, row=(lane>>4)*4+r
#pragma unroll
    for (int nf = 0; nf < 3; ++nf) {
        const int n = n0 + wn * 48 + nf * 16 + fr;
        const float bi = bias[n];
#pragma unroll
        for (int mf = 0; mf < 2; ++mf) {
            const int mrow = m0 + wm * 32 + mf * 16 + fg * 4;
#pragma unroll
            for (int r = 0; r < 4; ++r)
                gates[(size_t)(mrow + r) * 384 + n] = acc[mf][nf][r] + bi;
        }
    }
}

// ---------------------------------------------------------------------------
// pointwise: gates -> (hraw bf16, c f32, hbn bf16)   [4096 m][96 f]
// ---------------------------------------------------------------------------
__global__ __launch_bounds__(256) void pw(
    const float* __restrict__ gates, float* __restrict__ cst,
    u16* __restrict__ hraw, u16* __restrict__ hbn,
    const float* __restrict__ gam, const float* __restrict__ bet,
    const float* __restrict__ mu,  const float* __restrict__ var)
{
    const int idx = blockIdx.x * 256 + threadIdx.x;     // < 98304
    const int m = idx / 24, f0 = (idx - m * 24) * 4;
    const float* gb = gates + (size_t)m * 384 + f0;
    const f32x4 gi = *(const f32x4*)gb;
    const f32x4 gf = *(const f32x4*)(gb + 96);
    const f32x4 gc = *(const f32x4*)(gb + 192);
    const f32x4 go = *(const f32x4*)(gb + 288);
    float* cp = cst + m * 96 + f0;
    f32x4 cc = *(const f32x4*)cp;
    const f32x4 ga = *(const f32x4*)(gam + f0);
    const f32x4 be = *(const f32x4*)(bet + f0);
    const f32x4 mv = *(const f32x4*)(mu + f0);
    const f32x4 vv = *(const f32x4*)(var + f0);

    u16 hu[4], bu[4];
    f32x4 cn;
#pragma unroll
    for (int j = 0; j < 4; ++j) {
        const float i_ = hsig(gi[j]);
        const float f_ = hsig(gf[j]);
        const float o_ = hsig(go[j]);
        const float c_ = f_ * cc[j] + i_ * tanhf(gc[j]);
        const float h_ = o_ * tanhf(c_);
        cn[j] = c_;
        hu[j] = f2bf(h_);
        const float s = ga[j] * rsqrtf(vv[j] + 1e-3f);
        bu[j] = f2bf((h_ - mv[j]) * s + be[j]);
    }
    *(f32x4*)cp = cn;
    uint2 hp; hp.x = hu[0] | ((unsigned)hu[1] << 16); hp.y = hu[2] | ((unsigned)hu[3] << 16);
    uint2 bp; bp.x = bu[0] | ((unsigned)bu[1] << 16); bp.y = bu[2] | ((unsigned)bu[3] << 16);
    *(uint2*)(hraw + (size_t)m * 96 + f0) = hp;
    *(uint2*)(hbn  + (size_t)m * 96 + f0) = bp;
}

// ---------------------------------------------------------------------------
// dense over hall (bf16): out[b][nc] = sum_k flat[b][k] Wd[k][nc] + bd[nc]
// ---------------------------------------------------------------------------
__global__ void dense_partial(const u16* __restrict__ hall,
                              const float* __restrict__ Wd,
                              float* __restrict__ partial)
{
    const int k0 = blockIdx.x * 2048;
    const int tt = k0 / 24576;
    const int r0 = k0 - tt * 24576;
    const int t  = threadIdx.x;          // 0..159
    const int b  = t / 10;
    const int nc = t - b * 10;
    const u16* hp = hall + (size_t)(tt * 16 + b) * 24576 + r0;
    const float* wp = Wd + (size_t)k0 * 10 + nc;
    float acc = 0.0f;
    for (int j = 0; j < 2048; j += 8) {
        const u16x8 hv = *(const u16x8*)(hp + j);
#pragma unroll
        for (int u = 0; u < 8; ++u)
            acc = fmaf(bf2f(hv[u]), wp[(size_t)(j + u) * 10], acc);
    }
    partial[blockIdx.x * 160 + t] = acc;
}

__global__ void dense_reduce(const float* __restrict__ partial,
                             const float* __restrict__ bd,
                             float* __restrict__ out)
{
    const int t = threadIdx.x;           // 0..159
    const int nc = t - (t / 10) * 10;
    float acc = bd[nc];
    for (int p = 0; p < 768; ++p) acc += partial[p * 160 + t];
    out[t] = acc;
}

// ---------------------------------------------------------------------------
extern "C" void kernel_launch(void* const* d_in, const int* in_sizes, int n_in,
                              void* d_out, int out_size, void* d_ws, size_t ws_size,
                              hipStream_t stream)
{
    const float* x   = (const float*)d_in[0];
    const float* Wx0 = (const float*)d_in[1];
    const float* Wh0 = (const float*)d_in[2];
    const float* b0  = (const float*)d_in[3];
    const float* g0  = (const float*)d_in[4];
    const float* be0 = (const float*)d_in[5];
    const float* mu0 = (const float*)d_in[6];
    const float* v0  = (const float*)d_in[7];
    const float* Wx1 = (const float*)d_in[8];
    const float* Wh1 = (const float*)d_in[9];
    const float* b1  = (const float*)d_in[10];
    const float* g1  = (const float*)d_in[11];
    const float* be1 = (const float*)d_in[12];
    const float* mu1 = (const float*)d_in[13];
    const float* v1  = (const float*)d_in[14];
    const float* Wd  = (const float*)d_in[15];
    const float* bd  = (const float*)d_in[16];
    float* out = (float*)d_out;

    char* base = (char*)d_ws;
    u16*   h0    = (u16*)(base);                       //   786432 B
    u16*   h1    = (u16*)(base + 786432);              //   786432 B
    float* c0    = (float*)(base + 1572864);           //  1572864 B
    float* c1    = (float*)(base + 3145728);           //  1572864 B
    u16*   h0bn  = (u16*)(base + 4718592);             //   786432 B
    float* gates = (float*)(base + 5505024);           //  6291456 B
    u16*   xpad  = (u16*)(base + 11796480);            //  4194304 B
    u16*   Wt0   = (u16*)(base + 15990784);            //   737280 B
    u16*   Wt1   = (u16*)(base + 16728064);            //  1327104 B
    u16*   hall  = (u16*)(base + 18055168);            // 50331648 B
    float* part  = (float*)(base + 68386816);          //   491520 B

    // zero initial states h0,h1 (bf16) + c0,c1 (f32), contiguous
    hipMemsetAsync(base, 0, 4718592, stream);

    prep_x <<<1024, 256, 0, stream>>>(x, xpad);
    wtrans0<<<1440, 256, 0, stream>>>(Wx0, Wh0, Wt0);
    wtrans1<<<2592, 256, 0, stream>>>(Wx1, Wh1, Wt1);

    const dim3 cgrid(64, 4);
    for (int t = 0; t < 64; ++t) {
        conv_mfma<8><<<cgrid, 256, 0, stream>>>(
            xpad + (size_t)t * 32768, h0, Wt0, b0, gates);
        pw<<<384, 256, 0, stream>>>(gates, c0, h0, h0bn, g0, be0, mu0, v0);
        conv_mfma<96><<<cgrid, 256, 0, stream>>>(
            h0bn, h1, Wt1, b1, gates);
        pw<<<384, 256, 0, stream>>>(gates, c1, h1, hall + (size_t)t * 393216,
                                    g1, be1, mu1, v1);
    }

    dense_partial<<<768, 160, 0, stream>>>(hall, Wd, part);
    dense_reduce <<<1, 160, 0, stream>>>(part, bd, out);
}